// Round 9
// baseline (369.898 us; speedup 1.0000x reference)
//
#include <hip/hip_runtime.h>
#include <math.h>

#define Bc 16
#define Cc 96
#define Hh 128
#define Ww 128
#define NPIX 16384
#define Mm 12
#define CR 6
#define PAD 3

// conv tile geometry: 32 rows x 64 cols of output per 256-thread block,
// each thread produces 8 horizontal outputs via in-register sliding window.
#define CTH 32
#define CTW 64
#define TROWS 38          // CTH + 6
#define TCOLS 70          // CTW + 6
#define TSTRIDE 76        // padded: bank-group (3*ty+2*tx)%8 uniform -> conflict-free

// 8B vector load with honest 4B alignment (gfx950 unaligned global access
// emits global_load_dwordx2; fallback is 2x dword = no worse than before).
typedef float f2 __attribute__((ext_vector_type(2), aligned(4)));

// -------------------- K1: depthwise 7x7 conv + bias, per-block pool partials
__global__ __launch_bounds__(256) void k_conv(const float* __restrict__ x,
        const float* __restrict__ dw_w, const float* __restrict__ dw_b,
        float* __restrict__ f, float* __restrict__ partial) {
    const int bc = blockIdx.z;             // b*Cc + c
    const int c = bc % Cc;
    __shared__ float tile[TROWS * TSTRIDE];
    __shared__ float wts[49];
    __shared__ float red[256];
    const int tid = threadIdx.x;
    if (tid < 49) wts[tid] = dw_w[c * 49 + tid];
    const int ox0 = blockIdx.x * CTW, oy0 = blockIdx.y * CTH;
    const float* xp = x + (size_t)bc * NPIX;
    for (int i = tid; i < TROWS * TCOLS; i += 256) {
        int r = i / TCOLS, cc2 = i % TCOLS;
        int gy = oy0 + r - PAD, gx = ox0 + cc2 - PAD;
        float v = 0.f;
        if (gy >= 0 && gy < Hh && gx >= 0 && gx < Ww) v = xp[gy * Ww + gx];
        tile[r * TSTRIDE + cc2] = v;
    }
    __syncthreads();
    const int tx = tid & 7;    // col-group: outputs ox0 + tx*8 + 0..7
    const int ty = tid >> 3;   // output row 0..31
    const float bias = dw_b[c];
    float acc[8];
    #pragma unroll
    for (int j = 0; j < 8; ++j) acc[j] = bias;
    #pragma unroll
    for (int ky = 0; ky < 7; ++ky) {
        const float* rowp = &tile[(ty + ky) * TSTRIDE + tx * 8];
        float4 a = *(const float4*)(rowp);
        float4 b4 = *(const float4*)(rowp + 4);
        float4 c4 = *(const float4*)(rowp + 8);
        float4 d4 = *(const float4*)(rowp + 12);
        float win[16] = {a.x, a.y, a.z, a.w, b4.x, b4.y, b4.z, b4.w,
                         c4.x, c4.y, c4.z, c4.w, d4.x, d4.y, d4.z, d4.w};
        #pragma unroll
        for (int kx = 0; kx < 7; ++kx) {
            float w = wts[ky * 7 + kx];
            #pragma unroll
            for (int j = 0; j < 8; ++j)
                acc[j] = fmaf(win[kx + j], w, acc[j]);
        }
    }
    float* op = f + (size_t)bc * NPIX + (oy0 + ty) * Ww + ox0 + tx * 8;
    *(float4*)(op)     = make_float4(acc[0], acc[1], acc[2], acc[3]);
    *(float4*)(op + 4) = make_float4(acc[4], acc[5], acc[6], acc[7]);
    float s = 0.f;
    #pragma unroll
    for (int j = 0; j < 8; ++j) s += acc[j];
    red[tid] = s;
    __syncthreads();
    for (int st = 128; st > 0; st >>= 1) {
        if (tid < st) red[tid] += red[tid + st];
        __syncthreads();
    }
    if (tid == 0) partial[bc * 8 + blockIdx.y * 2 + blockIdx.x] = red[0];
}

// -------------------- K2: pooled mean -> SE attention; + centers copy to out
__global__ void k_attn(const float* __restrict__ partial,
        const float* __restrict__ ca_w1, const float* __restrict__ ca_w2,
        const float* __restrict__ centers,
        float* __restrict__ attn, float* __restrict__ out) {
    __shared__ float pm[Cc];
    __shared__ float hh[CR];
    const int tid = threadIdx.x;
    const int b = blockIdx.x;
    if (b == 0) {  // centers copy (output 2)
        const size_t base = (size_t)Bc * Cc * NPIX + (size_t)Bc * NPIX;
        for (int i = tid; i < Mm * Cc; i += 128) out[base + i] = centers[i];
    }
    if (tid < Cc) {
        float s = 0.f;
        const float* p = partial + (b * Cc + tid) * 8;
        #pragma unroll
        for (int i = 0; i < 8; ++i) s += p[i];
        pm[tid] = s * (1.0f / (float)NPIX);
    }
    __syncthreads();
    if (tid < CR) {
        float s = 0.f;
        for (int c0 = 0; c0 < Cc; ++c0) s = fmaf(ca_w1[tid * Cc + c0], pm[c0], s);
        hh[tid] = fmaxf(s, 0.f);
    }
    __syncthreads();
    if (tid < Cc) {
        float s = 0.f;
        #pragma unroll
        for (int r = 0; r < CR; ++r) s = fmaf(ca_w2[tid * CR + r], hh[r], s);
        attn[b * Cc + tid] = 1.0f / (1.0f + expf(-s));
    }
}

// fast exact-enough erf (Abramowitz-Stegun 7.1.26, |err|<=1.5e-7)
__device__ __forceinline__ float fast_gelu(float v) {
    float z = fabsf(v) * 0.70710678118654752440f;
    float t = 1.0f / fmaf(0.3275911f, z, 1.0f);
    float poly = t * fmaf(t, fmaf(t, fmaf(t, fmaf(t, 1.061405429f, -1.453152027f),
                          1.421413741f), -0.284496736f), 0.254829592f);
    float e = exp2f(-1.44269504088896340736f * z * z);
    float erfz = 1.0f - poly * e;
    erfz = (v < 0.0f) ? -erfz : erfz;
    return 0.5f * v * (1.0f + erfz);
}

// -------------------- K3: attn-scale + GELU + channel-LN + offset proj
__global__ __launch_bounds__(256) void k_ln_off(const float* __restrict__ f,
        const float* __restrict__ attn, const float* __restrict__ ln_g,
        const float* __restrict__ ln_b, const float* __restrict__ off_w,
        float* __restrict__ offs) {
    __shared__ float sa[Cc], sg[Cc], sb[Cc], sw0[Cc], sw1[Cc];
    const int tid = threadIdx.x;
    const int b = blockIdx.x >> 6;
    const int pix = ((blockIdx.x & 63) << 8) + tid;
    if (tid < Cc) {
        sa[tid] = attn[b * Cc + tid];
        sg[tid] = ln_g[tid];
        sb[tid] = ln_b[tid];
        sw0[tid] = off_w[tid];
        sw1[tid] = off_w[Cc + tid];
    }
    __syncthreads();
    const float* fp = f + (size_t)b * Cc * NPIX + pix;
    float u[Cc];
    float s1 = 0.f;
    #pragma unroll
    for (int c = 0; c < Cc; ++c) {
        float g = fast_gelu(fp[(size_t)c * NPIX] * sa[c]);
        u[c] = g;
        s1 += g;
    }
    float mu = s1 * (1.0f / (float)Cc);
    float s2 = 0.f;
    #pragma unroll
    for (int c = 0; c < Cc; ++c) { float d = u[c] - mu; s2 = fmaf(d, d, s2); }
    float rs = rsqrtf(s2 * (1.0f / (float)Cc) + 1e-5f);
    float o0 = 0.f, o1 = 0.f;
    #pragma unroll
    for (int c = 0; c < Cc; ++c) {
        float v = (u[c] - mu) * rs * sg[c] + sb[c];
        o0 = fmaf(sw0[c], v, o0);
        o1 = fmaf(sw1[c], v, o1);
    }
    offs[(size_t)b * 2 * NPIX + pix] = o0;
    offs[(size_t)b * 2 * NPIX + NPIX + pix] = o1;
}

// -------------------- K4: cosine-sim cluster assignment in FP64
// per-pixel 1/||x|| is a positive scalar -> cannot change argmax -> skipped.
__global__ __launch_bounds__(256) void k_group(const float* __restrict__ x,
        const float* __restrict__ centers, int* __restrict__ gid) {
    __shared__ double scn[Mm * Cc];
    const int tid = threadIdx.x;
    for (int i = tid; i < Mm * Cc; i += 256) scn[i] = (double)centers[i];
    __syncthreads();
    if (tid < Mm) {
        double ss = 0.0;
        #pragma unroll
        for (int c = 0; c < Cc; ++c) { double v = scn[tid * Cc + c]; ss += v * v; }
        double inv = 1.0 / fmax(sqrt(ss), 1e-12);
        #pragma unroll
        for (int c = 0; c < Cc; ++c) scn[tid * Cc + c] *= inv;
    }
    __syncthreads();
    const int b = blockIdx.x >> 6;
    const int n = ((blockIdx.x & 63) << 8) + tid;
    const float* xp = x + (size_t)b * Cc * NPIX + n;
    double acc[Mm];
    #pragma unroll
    for (int m = 0; m < Mm; ++m) acc[m] = 0.0;
    for (int c = 0; c < Cc; ++c) {
        double xv = (double)xp[(size_t)c * NPIX];
        #pragma unroll
        for (int m = 0; m < Mm; ++m) acc[m] = fma(xv, scn[m * Cc + c], acc[m]);
    }
    int bi = 0;
    double bv = acc[0];
    #pragma unroll
    for (int m = 1; m < Mm; ++m) {
        if (acc[m] > bv) { bv = acc[m]; bi = m; }
    }
    gid[(size_t)b * NPIX + n] = bi;
}

// -------------------- K5: stable counting sort -> inverse perm + float perm out
__global__ __launch_bounds__(256) void k_sort(const int* __restrict__ gid,
        int* __restrict__ iperm, float* __restrict__ out) {
    __shared__ int hist[256 * Mm];
    __shared__ int tot[Mm];
    const int t = threadIdx.x;
    const int b = blockIdx.x;
    for (int i = t; i < 256 * Mm; i += 256) hist[i] = 0;
    __syncthreads();
    const int* gp = gid + (size_t)b * NPIX;
    const int base = t * 64;
    for (int i = 0; i < 64; ++i) hist[t * Mm + gp[base + i]] += 1;
    __syncthreads();
    if (t < Mm) {
        int run = 0;
        for (int r = 0; r < 256; ++r) {
            int v = hist[r * Mm + t];
            hist[r * Mm + t] = run;
            run += v;
        }
        tot[t] = run;
    }
    __syncthreads();
    if (t == 0) {
        int run = 0;
        for (int m = 0; m < Mm; ++m) { int v = tot[m]; tot[m] = run; run += v; }
    }
    __syncthreads();
    int* ip = iperm + (size_t)b * NPIX;
    float* fperm = out + (size_t)Bc * Cc * NPIX + (size_t)b * NPIX;
    for (int i = 0; i < 64; ++i) {
        int src = base + i;
        int g = gp[src];
        int pos = tot[g] + hist[t * Mm + g];
        hist[t * Mm + g] += 1;
        ip[src] = pos;            // inverse permutation (scatter destination)
        fperm[pos] = (float)src;  // output 1: perm_indices as float
    }
}

// -------------------- K6: bilinear sample of x (+R bias), scatter via iperm
// L1-residency restructure (round-8 falsified the latency theory: dur was
// invariant to MLP depth & occupancy -> L1-miss request-rate bound).
// One block = one 1024-pixel band (8 rows), 1024 threads, grid 256 = 1
// block/CU. Channels SEQUENTIAL (unroll 2): per-channel tap window is
// 34 rows x 512B = 17KB -> fits L1 -> the ~2.3x intra-band line reuse and
// 4-taps-per-line hits actually land. XCD-chunked swizzle: 32 consecutive
// bands (= 2 whole batches) per XCD.
__global__ __launch_bounds__(1024, 4) void k_sample(const float* __restrict__ x,
        const float* __restrict__ R, const float* __restrict__ offs,
        const int* __restrict__ iperm, float* __restrict__ out) {
    const int lin = blockIdx.x;                    // 0..255
    const int swz = (lin & 7) * 32 + (lin >> 3);   // bijective (256 = 8*32)
    const int tid = threadIdx.x;
    const int b = swz >> 4;                        // 16 bands per batch
    const int pix = ((swz & 15) << 10) + tid;      // band*1024 + tid
    const int hh = pix >> 7, wwp = pix & 127;
    float o0 = offs[(size_t)b * 2 * NPIX + pix];
    float o1 = offs[(size_t)b * 2 * NPIX + NPIX + pix];
    float gx = -1.0f + (float)wwp * (2.0f / 127.0f) + o0;
    float gy = -1.0f + (float)hh * (2.0f / 127.0f) + o1;
    float px = fminf(fmaxf((gx + 1.0f) * ((float)Ww * 0.5f) - 0.5f, 0.0f), (float)(Ww - 1));
    float py = fminf(fmaxf((gy + 1.0f) * ((float)Hh * 0.5f) - 0.5f, 0.0f), (float)(Hh - 1));
    float x0f = floorf(px), y0f = floorf(py);
    float wx = px - x0f, wy = py - y0f;
    int x0 = (int)x0f, y0 = (int)y0f;
    int y1 = min(y0 + 1, Hh - 1);
    const bool hi = (x0 == Ww - 1);        // then wx == 0 exactly
    const int xb = hi ? (Ww - 2) : x0;     // 8B window [xb, xb+1]
    const int r0 = y0 * Ww + xb, r1 = y1 * Ww + xb;
    float rb;
    {
        f2 t0 = *(const f2*)(R + r0);
        f2 t1 = *(const f2*)(R + r1);
        float v00 = hi ? t0.y : t0.x, v01 = t0.y;
        float v10 = hi ? t1.y : t1.x, v11 = t1.y;
        float top = v00 * (1.0f - wx) + v01 * wx;
        float bot = v10 * (1.0f - wx) + v11 * wx;
        rb = top * (1.0f - wy) + bot * wy;
    }
    const int j = iperm[(size_t)b * NPIX + pix];
    const float* xc = x + (size_t)b * Cc * NPIX;
    float* op = out + (size_t)b * Cc * NPIX + j;
    #pragma unroll 2
    for (int c = 0; c < Cc; ++c) {
        f2 t0 = *(const f2*)(xc + r0);
        f2 t1 = *(const f2*)(xc + r1);
        float v00 = hi ? t0.y : t0.x, v01 = t0.y;
        float v10 = hi ? t1.y : t1.x, v11 = t1.y;
        float top = v00 * (1.0f - wx) + v01 * wx;
        float bot = v10 * (1.0f - wx) + v11 * wx;
        *op = top * (1.0f - wy) + bot * wy + rb;
        xc += NPIX;
        op += NPIX;
    }
}

extern "C" void kernel_launch(void* const* d_in, const int* in_sizes, int n_in,
                              void* d_out, int out_size, void* d_ws, size_t ws_size,
                              hipStream_t stream) {
    const float* x       = (const float*)d_in[0];
    const float* dw_w    = (const float*)d_in[1];
    const float* dw_b    = (const float*)d_in[2];
    const float* ca_w1   = (const float*)d_in[3];
    const float* ca_w2   = (const float*)d_in[4];
    const float* ln_g    = (const float*)d_in[5];
    const float* ln_b    = (const float*)d_in[6];
    const float* off_w   = (const float*)d_in[7];
    const float* R       = (const float*)d_in[8];
    const float* centers = (const float*)d_in[9];
    float* out = (float*)d_out;

    // workspace layout (~4.3 MB)
    float* partial = (float*)d_ws;                 // Bc*Cc*8
    float* attn    = partial + Bc * Cc * 8;        // Bc*Cc
    float* offs    = attn + Bc * Cc;               // Bc*2*NPIX
    int*   gid     = (int*)(offs + Bc * 2 * NPIX); // Bc*NPIX
    int*   iperm   = gid + Bc * NPIX;              // Bc*NPIX

    // conv output f lives in d_out's map region; dead after k_ln_off, then
    // safely overwritten by k_sample's permuted scatter writes.
    float* f = out;

    hipLaunchKernelGGL(k_conv, dim3(Ww / CTW, Hh / CTH, Bc * Cc), dim3(256), 0,
                       stream, x, dw_w, dw_b, f, partial);
    hipLaunchKernelGGL(k_attn, dim3(Bc), dim3(128), 0, stream,
                       partial, ca_w1, ca_w2, centers, attn, out);
    hipLaunchKernelGGL(k_ln_off, dim3(1024), dim3(256), 0, stream,
                       f, attn, ln_g, ln_b, off_w, offs);
    hipLaunchKernelGGL(k_group, dim3(1024), dim3(256), 0, stream, x, centers, gid);
    hipLaunchKernelGGL(k_sort, dim3(Bc), dim3(256), 0, stream, gid, iperm, out);
    hipLaunchKernelGGL(k_sample, dim3(256), dim3(1024), 0, stream,
                       x, R, offs, iperm, out);
}

// Round 10
// 357.977 us; speedup vs baseline: 1.0333x; 1.0333x over previous
//
#include <hip/hip_runtime.h>
#include <math.h>

#define Bc 16
#define Cc 96
#define Hh 128
#define Ww 128
#define NPIX 16384
#define Mm 12
#define CR 6
#define PAD 3

// conv tile geometry
#define CTH 32
#define CTW 64
#define TROWS 38
#define TCOLS 70
#define TSTRIDE 76

// fallback k_sample channel split
#define CGROUPS 6
#define CPG 16

typedef float f2 __attribute__((ext_vector_type(2), aligned(4)));

// -------------------- K1: depthwise 7x7 conv + bias, per-block pool partials
__global__ __launch_bounds__(256) void k_conv(const float* __restrict__ x,
        const float* __restrict__ dw_w, const float* __restrict__ dw_b,
        float* __restrict__ f, float* __restrict__ partial) {
    const int bc = blockIdx.z;
    const int c = bc % Cc;
    __shared__ float tile[TROWS * TSTRIDE];
    __shared__ float wts[49];
    __shared__ float red[256];
    const int tid = threadIdx.x;
    if (tid < 49) wts[tid] = dw_w[c * 49 + tid];
    const int ox0 = blockIdx.x * CTW, oy0 = blockIdx.y * CTH;
    const float* xp = x + (size_t)bc * NPIX;
    for (int i = tid; i < TROWS * TCOLS; i += 256) {
        int r = i / TCOLS, cc2 = i % TCOLS;
        int gy = oy0 + r - PAD, gx = ox0 + cc2 - PAD;
        float v = 0.f;
        if (gy >= 0 && gy < Hh && gx >= 0 && gx < Ww) v = xp[gy * Ww + gx];
        tile[r * TSTRIDE + cc2] = v;
    }
    __syncthreads();
    const int tx = tid & 7;
    const int ty = tid >> 3;
    const float bias = dw_b[c];
    float acc[8];
    #pragma unroll
    for (int j = 0; j < 8; ++j) acc[j] = bias;
    #pragma unroll
    for (int ky = 0; ky < 7; ++ky) {
        const float* rowp = &tile[(ty + ky) * TSTRIDE + tx * 8];
        float4 a = *(const float4*)(rowp);
        float4 b4 = *(const float4*)(rowp + 4);
        float4 c4 = *(const float4*)(rowp + 8);
        float4 d4 = *(const float4*)(rowp + 12);
        float win[16] = {a.x, a.y, a.z, a.w, b4.x, b4.y, b4.z, b4.w,
                         c4.x, c4.y, c4.z, c4.w, d4.x, d4.y, d4.z, d4.w};
        #pragma unroll
        for (int kx = 0; kx < 7; ++kx) {
            float w = wts[ky * 7 + kx];
            #pragma unroll
            for (int j = 0; j < 8; ++j)
                acc[j] = fmaf(win[kx + j], w, acc[j]);
        }
    }
    float* op = f + (size_t)bc * NPIX + (oy0 + ty) * Ww + ox0 + tx * 8;
    *(float4*)(op)     = make_float4(acc[0], acc[1], acc[2], acc[3]);
    *(float4*)(op + 4) = make_float4(acc[4], acc[5], acc[6], acc[7]);
    float s = 0.f;
    #pragma unroll
    for (int j = 0; j < 8; ++j) s += acc[j];
    red[tid] = s;
    __syncthreads();
    for (int st = 128; st > 0; st >>= 1) {
        if (tid < st) red[tid] += red[tid + st];
        __syncthreads();
    }
    if (tid == 0) partial[bc * 8 + blockIdx.y * 2 + blockIdx.x] = red[0];
}

// -------------------- K2: pooled mean -> SE attention; + centers copy to out
__global__ void k_attn(const float* __restrict__ partial,
        const float* __restrict__ ca_w1, const float* __restrict__ ca_w2,
        const float* __restrict__ centers,
        float* __restrict__ attn, float* __restrict__ out) {
    __shared__ float pm[Cc];
    __shared__ float hh[CR];
    const int tid = threadIdx.x;
    const int b = blockIdx.x;
    if (b == 0) {
        const size_t base = (size_t)Bc * Cc * NPIX + (size_t)Bc * NPIX;
        for (int i = tid; i < Mm * Cc; i += 128) out[base + i] = centers[i];
    }
    if (tid < Cc) {
        float s = 0.f;
        const float* p = partial + (b * Cc + tid) * 8;
        #pragma unroll
        for (int i = 0; i < 8; ++i) s += p[i];
        pm[tid] = s * (1.0f / (float)NPIX);
    }
    __syncthreads();
    if (tid < CR) {
        float s = 0.f;
        for (int c0 = 0; c0 < Cc; ++c0) s = fmaf(ca_w1[tid * Cc + c0], pm[c0], s);
        hh[tid] = fmaxf(s, 0.f);
    }
    __syncthreads();
    if (tid < Cc) {
        float s = 0.f;
        #pragma unroll
        for (int r = 0; r < CR; ++r) s = fmaf(ca_w2[tid * CR + r], hh[r], s);
        attn[b * Cc + tid] = 1.0f / (1.0f + expf(-s));
    }
}

// fast erf (A&S 7.1.26, |err|<=1.5e-7)
__device__ __forceinline__ float fast_gelu(float v) {
    float z = fabsf(v) * 0.70710678118654752440f;
    float t = 1.0f / fmaf(0.3275911f, z, 1.0f);
    float poly = t * fmaf(t, fmaf(t, fmaf(t, fmaf(t, 1.061405429f, -1.453152027f),
                          1.421413741f), -0.284496736f), 0.254829592f);
    float e = exp2f(-1.44269504088896340736f * z * z);
    float erfz = 1.0f - poly * e;
    erfz = (v < 0.0f) ? -erfz : erfz;
    return 0.5f * v * (1.0f + erfz);
}

// -------------------- K3: attn-scale + GELU + channel-LN + offset proj
__global__ __launch_bounds__(256) void k_ln_off(const float* __restrict__ f,
        const float* __restrict__ attn, const float* __restrict__ ln_g,
        const float* __restrict__ ln_b, const float* __restrict__ off_w,
        float* __restrict__ offs) {
    __shared__ float sa[Cc], sg[Cc], sb[Cc], sw0[Cc], sw1[Cc];
    const int tid = threadIdx.x;
    const int b = blockIdx.x >> 6;
    const int pix = ((blockIdx.x & 63) << 8) + tid;
    if (tid < Cc) {
        sa[tid] = attn[b * Cc + tid];
        sg[tid] = ln_g[tid];
        sb[tid] = ln_b[tid];
        sw0[tid] = off_w[tid];
        sw1[tid] = off_w[Cc + tid];
    }
    __syncthreads();
    const float* fp = f + (size_t)b * Cc * NPIX + pix;
    float u[Cc];
    float s1 = 0.f;
    #pragma unroll
    for (int c = 0; c < Cc; ++c) {
        float g = fast_gelu(fp[(size_t)c * NPIX] * sa[c]);
        u[c] = g;
        s1 += g;
    }
    float mu = s1 * (1.0f / (float)Cc);
    float s2 = 0.f;
    #pragma unroll
    for (int c = 0; c < Cc; ++c) { float d = u[c] - mu; s2 = fmaf(d, d, s2); }
    float rs = rsqrtf(s2 * (1.0f / (float)Cc) + 1e-5f);
    float o0 = 0.f, o1 = 0.f;
    #pragma unroll
    for (int c = 0; c < Cc; ++c) {
        float v = (u[c] - mu) * rs * sg[c] + sb[c];
        o0 = fmaf(sw0[c], v, o0);
        o1 = fmaf(sw1[c], v, o1);
    }
    offs[(size_t)b * 2 * NPIX + pix] = o0;
    offs[(size_t)b * 2 * NPIX + NPIX + pix] = o1;
}

// -------------------- K4: FP64 cosine argmax; optionally emits x_nhwc
// (do_nhwc): while streaming x it writes x_nhwc[b][pix][c] (float4-buffered;
// per-lane 384B-apart stores, fully covered in aggregate -> L2 assembles lines).
__global__ __launch_bounds__(256) void k_group(const float* __restrict__ x,
        const float* __restrict__ centers, int* __restrict__ gid,
        float* __restrict__ xnh, const int do_nhwc) {
    __shared__ double scn[Mm * Cc];
    const int tid = threadIdx.x;
    for (int i = tid; i < Mm * Cc; i += 256) scn[i] = (double)centers[i];
    __syncthreads();
    if (tid < Mm) {
        double ss = 0.0;
        #pragma unroll
        for (int c = 0; c < Cc; ++c) { double v = scn[tid * Cc + c]; ss += v * v; }
        double inv = 1.0 / fmax(sqrt(ss), 1e-12);
        #pragma unroll
        for (int c = 0; c < Cc; ++c) scn[tid * Cc + c] *= inv;
    }
    __syncthreads();
    const int b = blockIdx.x >> 6;
    const int n = ((blockIdx.x & 63) << 8) + tid;
    const float* xp = x + (size_t)b * Cc * NPIX + n;
    float* xo = xnh + (size_t)b * NPIX * Cc + (size_t)n * Cc;
    double acc[Mm];
    #pragma unroll
    for (int m = 0; m < Mm; ++m) acc[m] = 0.0;
    float4 q;
    #pragma unroll 4
    for (int c = 0; c < Cc; ++c) {
        float xf = xp[(size_t)c * NPIX];
        ((float*)&q)[c & 3] = xf;
        if ((c & 3) == 3 && do_nhwc) *(float4*)(xo + (c - 3)) = q;
        double xv = (double)xf;
        #pragma unroll
        for (int m = 0; m < Mm; ++m) acc[m] = fma(xv, scn[m * Cc + c], acc[m]);
    }
    int bi = 0;
    double bv = acc[0];
    #pragma unroll
    for (int m = 1; m < Mm; ++m) {
        if (acc[m] > bv) { bv = acc[m]; bi = m; }
    }
    gid[(size_t)b * NPIX + n] = bi;
}

// -------------------- K5: stable counting sort -> inverse perm + float perm out
__global__ __launch_bounds__(256) void k_sort(const int* __restrict__ gid,
        int* __restrict__ iperm, float* __restrict__ out) {
    __shared__ int hist[256 * Mm];
    __shared__ int tot[Mm];
    const int t = threadIdx.x;
    const int b = blockIdx.x;
    for (int i = t; i < 256 * Mm; i += 256) hist[i] = 0;
    __syncthreads();
    const int* gp = gid + (size_t)b * NPIX;
    const int base = t * 64;
    for (int i = 0; i < 64; ++i) hist[t * Mm + gp[base + i]] += 1;
    __syncthreads();
    if (t < Mm) {
        int run = 0;
        for (int r = 0; r < 256; ++r) {
            int v = hist[r * Mm + t];
            hist[r * Mm + t] = run;
            run += v;
        }
        tot[t] = run;
    }
    __syncthreads();
    if (t == 0) {
        int run = 0;
        for (int m = 0; m < Mm; ++m) { int v = tot[m]; tot[m] = run; run += v; }
    }
    __syncthreads();
    int* ip = iperm + (size_t)b * NPIX;
    float* fperm = out + (size_t)Bc * Cc * NPIX + (size_t)b * NPIX;
    for (int i = 0; i < 64; ++i) {
        int src = base + i;
        int g = gp[src];
        int pos = tot[g] + hist[t * Mm + g];
        hist[t * Mm + g] += 1;
        ip[src] = pos;
        fperm[pos] = (float)src;
    }
}

// -------------------- K6-FAST: NHWC bilinear sample + permuted NCHW write
// L2-line-BW bound fix: per pixel the 4 taps x 96 ch are TWO contiguous 768B
// spans of x_nhwc (100% line utilization; ~8x less L2 traffic than the NCHW
// gather). 64 px/block; results staged in LDS [64][97] (pad -> conflict-free)
// then written NCHW with runny j-scatter (same store pattern as fallback).
__global__ __launch_bounds__(256) void k_sample_nhwc(
        const float* __restrict__ xnh, const float* __restrict__ R,
        const float* __restrict__ offs, const int* __restrict__ iperm,
        float* __restrict__ out) {
    const int lin = blockIdx.x;                    // 0..4095
    const int swz = (lin & 7) * 512 + (lin >> 3);  // bijective: 2 batches/XCD
    const int b = swz >> 8;
    const int pixbase = (swz & 255) * 64;
    __shared__ float lds[64 * 97];
    __shared__ float swx[64], swy[64], srb[64];
    __shared__ int sr0[64], sr1[64], shi[64], sj[64];
    const int t = threadIdx.x;
    if (t < 64) {
        const int pix = pixbase + t;
        const int hh = pix >> 7, wwp = pix & 127;
        float o0 = offs[(size_t)b * 2 * NPIX + pix];
        float o1 = offs[(size_t)b * 2 * NPIX + NPIX + pix];
        float gx = -1.0f + (float)wwp * (2.0f / 127.0f) + o0;
        float gy = -1.0f + (float)hh * (2.0f / 127.0f) + o1;
        float px = fminf(fmaxf((gx + 1.0f) * ((float)Ww * 0.5f) - 0.5f, 0.0f), (float)(Ww - 1));
        float py = fminf(fmaxf((gy + 1.0f) * ((float)Hh * 0.5f) - 0.5f, 0.0f), (float)(Hh - 1));
        float x0f = floorf(px), y0f = floorf(py);
        float wx = px - x0f, wy = py - y0f;
        int x0 = (int)x0f, y0 = (int)y0f;
        int y1 = min(y0 + 1, Hh - 1);
        const bool hi = (x0 == Ww - 1);
        const int xb = hi ? (Ww - 2) : x0;
        const int r0 = y0 * Ww + xb, r1 = y1 * Ww + xb;
        float rb;
        {
            f2 t0 = *(const f2*)(R + r0);
            f2 t1 = *(const f2*)(R + r1);
            float v00 = hi ? t0.y : t0.x, v01 = t0.y;
            float v10 = hi ? t1.y : t1.x, v11 = t1.y;
            float top = v00 * (1.0f - wx) + v01 * wx;
            float bot = v10 * (1.0f - wx) + v11 * wx;
            rb = top * (1.0f - wy) + bot * wy;
        }
        swx[t] = wx; swy[t] = wy; srb[t] = rb;
        sr0[t] = r0 * Cc; sr1[t] = r1 * Cc;
        shi[t] = hi ? 1 : 0;
        sj[t] = iperm[(size_t)b * NPIX + pix];
    }
    __syncthreads();
    {
        const int px = t >> 2, part = t & 3;
        const float wx = swx[px], wy = swy[px], rb = srb[px];
        const bool hi = shi[px] != 0;
        const float* base0 = xnh + (size_t)b * NPIX * Cc + sr0[px];
        const float* base1 = xnh + (size_t)b * NPIX * Cc + sr1[px];
        float* lp = &lds[px * 97 + part * 24];
        #pragma unroll
        for (int i = 0; i < 6; ++i) {
            const int c = part * 24 + i * 4;
            float4 A = *(const float4*)(base0 + c);
            float4 B = *(const float4*)(base0 + Cc + c);
            float4 C = *(const float4*)(base1 + c);
            float4 D = *(const float4*)(base1 + Cc + c);
            #pragma unroll
            for (int k = 0; k < 4; ++k) {
                float a = ((const float*)&A)[k], bb = ((const float*)&B)[k];
                float cc = ((const float*)&C)[k], dd = ((const float*)&D)[k];
                float v00 = hi ? bb : a,  v01 = bb;
                float v10 = hi ? dd : cc, v11 = dd;
                float top = v00 * (1.0f - wx) + v01 * wx;
                float bot = v10 * (1.0f - wx) + v11 * wx;
                lp[i * 4 + k] = top * (1.0f - wy) + bot * wy + rb;
            }
        }
    }
    __syncthreads();
    {
        const int px2 = t & 63, cq = t >> 6;
        const int jj = sj[px2];
        float* ob = out + (size_t)b * Cc * NPIX + jj;
        const float* lp = &lds[px2 * 97 + cq * 24];
        #pragma unroll
        for (int i = 0; i < 24; ++i) {
            const int c = cq * 24 + i;
            ob[(size_t)c * NPIX] = lp[i];
        }
    }
}

// -------------------- K6-FALLBACK: round-7 NCHW sampler (142.9us proven)
__global__ __launch_bounds__(256, 4) void k_sample(const float* __restrict__ x,
        const float* __restrict__ R, const float* __restrict__ offs,
        const int* __restrict__ iperm, float* __restrict__ out) {
    const int lin = blockIdx.x;
    const int swz = (lin & 7) * 128 + (lin >> 3);
    const int tid = threadIdx.x;
    const int b = swz >> 6;
    const int pix = ((swz & 63) << 8) + tid;
    const int hh = pix >> 7, wwp = pix & 127;
    float o0 = offs[(size_t)b * 2 * NPIX + pix];
    float o1 = offs[(size_t)b * 2 * NPIX + NPIX + pix];
    float gx = -1.0f + (float)wwp * (2.0f / 127.0f) + o0;
    float gy = -1.0f + (float)hh * (2.0f / 127.0f) + o1;
    float px = fminf(fmaxf((gx + 1.0f) * ((float)Ww * 0.5f) - 0.5f, 0.0f), (float)(Ww - 1));
    float py = fminf(fmaxf((gy + 1.0f) * ((float)Hh * 0.5f) - 0.5f, 0.0f), (float)(Hh - 1));
    float x0f = floorf(px), y0f = floorf(py);
    float wx = px - x0f, wy = py - y0f;
    int x0 = (int)x0f, y0 = (int)y0f;
    int y1 = min(y0 + 1, Hh - 1);
    const bool hi = (x0 == Ww - 1);
    const int xb = hi ? (Ww - 2) : x0;
    const int r0 = y0 * Ww + xb, r1 = y1 * Ww + xb;
    float rb;
    {
        f2 t0 = *(const f2*)(R + r0);
        f2 t1 = *(const f2*)(R + r1);
        float v00 = hi ? t0.y : t0.x, v01 = t0.y;
        float v10 = hi ? t1.y : t1.x, v11 = t1.y;
        float top = v00 * (1.0f - wx) + v01 * wx;
        float bot = v10 * (1.0f - wx) + v11 * wx;
        rb = top * (1.0f - wy) + bot * wy;
    }
    const int c0 = blockIdx.y * CPG;
    const int j = iperm[(size_t)b * NPIX + pix];
    const float* xp = x + (size_t)b * Cc * NPIX + (size_t)c0 * NPIX;
    float* op = out + (size_t)b * Cc * NPIX + (size_t)c0 * NPIX + j;
    f2 t0[CPG], t1[CPG];
    #pragma unroll
    for (int c = 0; c < CPG; ++c) {
        const float* xc = xp + (size_t)c * NPIX;
        t0[c] = *(const f2*)(xc + r0);
        t1[c] = *(const f2*)(xc + r1);
    }
    #pragma unroll
    for (int c = 0; c < CPG; ++c) {
        float v00 = hi ? t0[c].y : t0[c].x, v01 = t0[c].y;
        float v10 = hi ? t1[c].y : t1[c].x, v11 = t1[c].y;
        float top = v00 * (1.0f - wx) + v01 * wx;
        float bot = v10 * (1.0f - wx) + v11 * wx;
        op[(size_t)c * NPIX] = top * (1.0f - wy) + bot * wy + rb;
    }
}

extern "C" void kernel_launch(void* const* d_in, const int* in_sizes, int n_in,
                              void* d_out, int out_size, void* d_ws, size_t ws_size,
                              hipStream_t stream) {
    const float* x       = (const float*)d_in[0];
    const float* dw_w    = (const float*)d_in[1];
    const float* dw_b    = (const float*)d_in[2];
    const float* ca_w1   = (const float*)d_in[3];
    const float* ca_w2   = (const float*)d_in[4];
    const float* ln_g    = (const float*)d_in[5];
    const float* ln_b    = (const float*)d_in[6];
    const float* off_w   = (const float*)d_in[7];
    const float* R       = (const float*)d_in[8];
    const float* centers = (const float*)d_in[9];
    float* out = (float*)d_out;

    // workspace: small region (4.25MB) + optional x_nhwc (100.7MB)
    float* partial = (float*)d_ws;                 // Bc*Cc*8
    float* attn    = partial + Bc * Cc * 8;        // Bc*Cc
    float* offs    = attn + Bc * Cc;               // Bc*2*NPIX
    int*   gid     = (int*)(offs + Bc * 2 * NPIX); // Bc*NPIX
    int*   iperm   = gid + Bc * NPIX;              // Bc*NPIX
    float* xnh     = (float*)(iperm + Bc * NPIX);  // Bc*NPIX*Cc (optional)

    const size_t small_elems = (size_t)Bc * Cc * 8 + Bc * Cc +
                               (size_t)Bc * 2 * NPIX + 2 * (size_t)Bc * NPIX;
    const size_t need = (small_elems + (size_t)Bc * NPIX * Cc) * 4;
    const int do_nhwc = (ws_size >= need) ? 1 : 0;

    float* f = out;  // conv output lives in out's map region (dead after ln_off)

    hipLaunchKernelGGL(k_conv, dim3(Ww / CTW, Hh / CTH, Bc * Cc), dim3(256), 0,
                       stream, x, dw_w, dw_b, f, partial);
    hipLaunchKernelGGL(k_attn, dim3(Bc), dim3(128), 0, stream,
                       partial, ca_w1, ca_w2, centers, attn, out);
    hipLaunchKernelGGL(k_ln_off, dim3(1024), dim3(256), 0, stream,
                       f, attn, ln_g, ln_b, off_w, offs);
    hipLaunchKernelGGL(k_group, dim3(1024), dim3(256), 0, stream,
                       x, centers, gid, xnh, do_nhwc);
    hipLaunchKernelGGL(k_sort, dim3(Bc), dim3(256), 0, stream, gid, iperm, out);
    if (do_nhwc) {
        hipLaunchKernelGGL(k_sample_nhwc, dim3(4096), dim3(256), 0, stream,
                           xnh, R, offs, iperm, out);
    } else {
        hipLaunchKernelGGL(k_sample, dim3(1024, CGROUPS), dim3(256), 0, stream,
                           x, R, offs, iperm, out);
    }
}

// Round 11
// 342.240 us; speedup vs baseline: 1.0808x; 1.0460x over previous
//
#include <hip/hip_runtime.h>
#include <math.h>

#define Bc 16
#define Cc 96
#define Hh 128
#define Ww 128
#define NPIX 16384
#define Mm 12
#define CR 6
#define PAD 3

// conv tile geometry
#define CTH 32
#define CTW 64
#define TROWS 38
#define TCOLS 70
#define TSTRIDE 76

// fallback k_sample channel split
#define CGROUPS 6
#define CPG 16

typedef float f2 __attribute__((ext_vector_type(2), aligned(4)));

// -------------------- K1: depthwise 7x7 conv + bias, per-block pool partials
__global__ __launch_bounds__(256) void k_conv(const float* __restrict__ x,
        const float* __restrict__ dw_w, const float* __restrict__ dw_b,
        float* __restrict__ f, float* __restrict__ partial) {
    const int bc = blockIdx.z;
    const int c = bc % Cc;
    __shared__ float tile[TROWS * TSTRIDE];
    __shared__ float wts[49];
    __shared__ float red[256];
    const int tid = threadIdx.x;
    if (tid < 49) wts[tid] = dw_w[c * 49 + tid];
    const int ox0 = blockIdx.x * CTW, oy0 = blockIdx.y * CTH;
    const float* xp = x + (size_t)bc * NPIX;
    for (int i = tid; i < TROWS * TCOLS; i += 256) {
        int r = i / TCOLS, cc2 = i % TCOLS;
        int gy = oy0 + r - PAD, gx = ox0 + cc2 - PAD;
        float v = 0.f;
        if (gy >= 0 && gy < Hh && gx >= 0 && gx < Ww) v = xp[gy * Ww + gx];
        tile[r * TSTRIDE + cc2] = v;
    }
    __syncthreads();
    const int tx = tid & 7;
    const int ty = tid >> 3;
    const float bias = dw_b[c];
    float acc[8];
    #pragma unroll
    for (int j = 0; j < 8; ++j) acc[j] = bias;
    #pragma unroll
    for (int ky = 0; ky < 7; ++ky) {
        const float* rowp = &tile[(ty + ky) * TSTRIDE + tx * 8];
        float4 a = *(const float4*)(rowp);
        float4 b4 = *(const float4*)(rowp + 4);
        float4 c4 = *(const float4*)(rowp + 8);
        float4 d4 = *(const float4*)(rowp + 12);
        float win[16] = {a.x, a.y, a.z, a.w, b4.x, b4.y, b4.z, b4.w,
                         c4.x, c4.y, c4.z, c4.w, d4.x, d4.y, d4.z, d4.w};
        #pragma unroll
        for (int kx = 0; kx < 7; ++kx) {
            float w = wts[ky * 7 + kx];
            #pragma unroll
            for (int j = 0; j < 8; ++j)
                acc[j] = fmaf(win[kx + j], w, acc[j]);
        }
    }
    float* op = f + (size_t)bc * NPIX + (oy0 + ty) * Ww + ox0 + tx * 8;
    *(float4*)(op)     = make_float4(acc[0], acc[1], acc[2], acc[3]);
    *(float4*)(op + 4) = make_float4(acc[4], acc[5], acc[6], acc[7]);
    float s = 0.f;
    #pragma unroll
    for (int j = 0; j < 8; ++j) s += acc[j];
    red[tid] = s;
    __syncthreads();
    for (int st = 128; st > 0; st >>= 1) {
        if (tid < st) red[tid] += red[tid + st];
        __syncthreads();
    }
    if (tid == 0) partial[bc * 8 + blockIdx.y * 2 + blockIdx.x] = red[0];
}

// -------------------- K2: pooled mean -> SE attention; + centers copy to out
__global__ void k_attn(const float* __restrict__ partial,
        const float* __restrict__ ca_w1, const float* __restrict__ ca_w2,
        const float* __restrict__ centers,
        float* __restrict__ attn, float* __restrict__ out) {
    __shared__ float pm[Cc];
    __shared__ float hh[CR];
    const int tid = threadIdx.x;
    const int b = blockIdx.x;
    if (b == 0) {
        const size_t base = (size_t)Bc * Cc * NPIX + (size_t)Bc * NPIX;
        for (int i = tid; i < Mm * Cc; i += 128) out[base + i] = centers[i];
    }
    if (tid < Cc) {
        float s = 0.f;
        const float* p = partial + (b * Cc + tid) * 8;
        #pragma unroll
        for (int i = 0; i < 8; ++i) s += p[i];
        pm[tid] = s * (1.0f / (float)NPIX);
    }
    __syncthreads();
    if (tid < CR) {
        float s = 0.f;
        for (int c0 = 0; c0 < Cc; ++c0) s = fmaf(ca_w1[tid * Cc + c0], pm[c0], s);
        hh[tid] = fmaxf(s, 0.f);
    }
    __syncthreads();
    if (tid < Cc) {
        float s = 0.f;
        #pragma unroll
        for (int r = 0; r < CR; ++r) s = fmaf(ca_w2[tid * CR + r], hh[r], s);
        attn[b * Cc + tid] = 1.0f / (1.0f + expf(-s));
    }
}

// fast erf (A&S 7.1.26, |err|<=1.5e-7)
__device__ __forceinline__ float fast_gelu(float v) {
    float z = fabsf(v) * 0.70710678118654752440f;
    float t = 1.0f / fmaf(0.3275911f, z, 1.0f);
    float poly = t * fmaf(t, fmaf(t, fmaf(t, fmaf(t, 1.061405429f, -1.453152027f),
                          1.421413741f), -0.284496736f), 0.254829592f);
    float e = exp2f(-1.44269504088896340736f * z * z);
    float erfz = 1.0f - poly * e;
    erfz = (v < 0.0f) ? -erfz : erfz;
    return 0.5f * v * (1.0f + erfz);
}

// -------------------- K3: attn-scale + GELU + channel-LN + offset proj
__global__ __launch_bounds__(256) void k_ln_off(const float* __restrict__ f,
        const float* __restrict__ attn, const float* __restrict__ ln_g,
        const float* __restrict__ ln_b, const float* __restrict__ off_w,
        float* __restrict__ offs) {
    __shared__ float sa[Cc], sg[Cc], sb[Cc], sw0[Cc], sw1[Cc];
    const int tid = threadIdx.x;
    const int b = blockIdx.x >> 6;
    const int pix = ((blockIdx.x & 63) << 8) + tid;
    if (tid < Cc) {
        sa[tid] = attn[b * Cc + tid];
        sg[tid] = ln_g[tid];
        sb[tid] = ln_b[tid];
        sw0[tid] = off_w[tid];
        sw1[tid] = off_w[Cc + tid];
    }
    __syncthreads();
    const float* fp = f + (size_t)b * Cc * NPIX + pix;
    float u[Cc];
    float s1 = 0.f;
    #pragma unroll
    for (int c = 0; c < Cc; ++c) {
        float g = fast_gelu(fp[(size_t)c * NPIX] * sa[c]);
        u[c] = g;
        s1 += g;
    }
    float mu = s1 * (1.0f / (float)Cc);
    float s2 = 0.f;
    #pragma unroll
    for (int c = 0; c < Cc; ++c) { float d = u[c] - mu; s2 = fmaf(d, d, s2); }
    float rs = rsqrtf(s2 * (1.0f / (float)Cc) + 1e-5f);
    float o0 = 0.f, o1 = 0.f;
    #pragma unroll
    for (int c = 0; c < Cc; ++c) {
        float v = (u[c] - mu) * rs * sg[c] + sb[c];
        o0 = fmaf(sw0[c], v, o0);
        o1 = fmaf(sw1[c], v, o1);
    }
    offs[(size_t)b * 2 * NPIX + pix] = o0;
    offs[(size_t)b * 2 * NPIX + NPIX + pix] = o1;
}

// -------------------- K4: FP64 cosine argmax (clean round-7 form)
__global__ __launch_bounds__(256) void k_group(const float* __restrict__ x,
        const float* __restrict__ centers, int* __restrict__ gid) {
    __shared__ double scn[Mm * Cc];
    const int tid = threadIdx.x;
    for (int i = tid; i < Mm * Cc; i += 256) scn[i] = (double)centers[i];
    __syncthreads();
    if (tid < Mm) {
        double ss = 0.0;
        #pragma unroll
        for (int c = 0; c < Cc; ++c) { double v = scn[tid * Cc + c]; ss += v * v; }
        double inv = 1.0 / fmax(sqrt(ss), 1e-12);
        #pragma unroll
        for (int c = 0; c < Cc; ++c) scn[tid * Cc + c] *= inv;
    }
    __syncthreads();
    const int b = blockIdx.x >> 6;
    const int n = ((blockIdx.x & 63) << 8) + tid;
    const float* xp = x + (size_t)b * Cc * NPIX + n;
    double acc[Mm];
    #pragma unroll
    for (int m = 0; m < Mm; ++m) acc[m] = 0.0;
    for (int c = 0; c < Cc; ++c) {
        double xv = (double)xp[(size_t)c * NPIX];
        #pragma unroll
        for (int m = 0; m < Mm; ++m) acc[m] = fma(xv, scn[m * Cc + c], acc[m]);
    }
    int bi = 0;
    double bv = acc[0];
    #pragma unroll
    for (int m = 1; m < Mm; ++m) {
        if (acc[m] > bv) { bv = acc[m]; bi = m; }
    }
    gid[(size_t)b * NPIX + n] = bi;
}

// -------------------- K5: stable counting sort -> iperm, int perm, float perm
__global__ __launch_bounds__(256) void k_sort(const int* __restrict__ gid,
        int* __restrict__ iperm, int* __restrict__ permi, float* __restrict__ out) {
    __shared__ int hist[256 * Mm];
    __shared__ int tot[Mm];
    const int t = threadIdx.x;
    const int b = blockIdx.x;
    for (int i = t; i < 256 * Mm; i += 256) hist[i] = 0;
    __syncthreads();
    const int* gp = gid + (size_t)b * NPIX;
    const int base = t * 64;
    for (int i = 0; i < 64; ++i) hist[t * Mm + gp[base + i]] += 1;
    __syncthreads();
    if (t < Mm) {
        int run = 0;
        for (int r = 0; r < 256; ++r) {
            int v = hist[r * Mm + t];
            hist[r * Mm + t] = run;
            run += v;
        }
        tot[t] = run;
    }
    __syncthreads();
    if (t == 0) {
        int run = 0;
        for (int m = 0; m < Mm; ++m) { int v = tot[m]; tot[m] = run; run += v; }
    }
    __syncthreads();
    int* ip = iperm + (size_t)b * NPIX;
    int* pi = permi + (size_t)b * NPIX;
    float* fperm = out + (size_t)Bc * Cc * NPIX + (size_t)b * NPIX;
    for (int i = 0; i < 64; ++i) {
        int src = base + i;
        int g = gp[src];
        int pos = tot[g] + hist[t * Mm + g];
        hist[t * Mm + g] += 1;
        ip[src] = pos;            // inverse perm (fallback scatter path)
        pi[pos] = src;            // forward perm (output-ordered sampler)
        fperm[pos] = (float)src;  // output 1: perm_indices as float
    }
}

// -------------------- K-TR: NCHW -> NHWC transpose, coalesced both sides
// block = one 128-px strip of one batch; LDS [96][129] (stride 129 = 1 mod 32
// -> conflict-light). Reads: lanes = consecutive px. Writes: float4 at
// gpos = px*96+c, lane-contiguous -> 1KB/wave fully covered.
__global__ __launch_bounds__(256) void k_tr(const float* __restrict__ x,
        float* __restrict__ xnh) {
    __shared__ float lds[Cc * 129];
    const int bid = blockIdx.x;          // 0..2047
    const int b = bid >> 7;
    const int p0 = (bid & 127) * 128;
    const int t = threadIdx.x;
    const int px = t & 127, crow = t >> 7;
    const float* xp = x + (size_t)b * Cc * NPIX + p0 + px;
    #pragma unroll
    for (int it = 0; it < 48; ++it) {
        const int c = it * 2 + crow;
        lds[c * 129 + px] = xp[(size_t)c * NPIX];
    }
    __syncthreads();
    float* ob = xnh + (size_t)b * NPIX * Cc + (size_t)p0 * Cc;
    #pragma unroll
    for (int i = 0; i < 12; ++i) {
        const int idx = i * 256 + t;     // float4 index
        const int gpos = idx * 4;        // = px*96 + c (c multiple of 4)
        const int ppx = gpos / 96;
        const int c = gpos - ppx * 96;
        float4 v = make_float4(lds[(c + 0) * 129 + ppx], lds[(c + 1) * 129 + ppx],
                               lds[(c + 2) * 129 + ppx], lds[(c + 3) * 129 + ppx]);
        *(float4*)(ob + gpos) = v;
    }
}

// -------------------- K6-FAST: output-position-ordered NHWC sampler
// Iterates over SORTED positions jj: src = perm[jj]. Writes are fully
// coalesced (out[c*NPIX + jbase + lane], 256B/wave covered) — kills the
// 1.58x write amplification of the src-ordered scatter. Reads: two 768B
// x_nhwc spans per pixel (L3-resident), offs/R as 4B gathers.
__global__ __launch_bounds__(256) void k_sample_nhwc(
        const float* __restrict__ xnh, const float* __restrict__ R,
        const float* __restrict__ offs, const int* __restrict__ permi,
        float* __restrict__ out) {
    const int lin = blockIdx.x;                    // 0..4095
    const int swz = (lin & 7) * 512 + (lin >> 3);  // 2 batches per XCD
    const int b = swz >> 8;
    const int jbase = (swz & 255) * 64;
    __shared__ float lds[64 * 97];
    __shared__ float swx[64], swy[64], srb[64];
    __shared__ int sr0[64], sr1[64], shi[64];
    const int t = threadIdx.x;
    if (t < 64) {
        const int src = permi[(size_t)b * NPIX + jbase + t];
        const int hh = src >> 7, wwp = src & 127;
        float o0 = offs[(size_t)b * 2 * NPIX + src];
        float o1 = offs[(size_t)b * 2 * NPIX + NPIX + src];
        float gx = -1.0f + (float)wwp * (2.0f / 127.0f) + o0;
        float gy = -1.0f + (float)hh * (2.0f / 127.0f) + o1;
        float px = fminf(fmaxf((gx + 1.0f) * ((float)Ww * 0.5f) - 0.5f, 0.0f), (float)(Ww - 1));
        float py = fminf(fmaxf((gy + 1.0f) * ((float)Hh * 0.5f) - 0.5f, 0.0f), (float)(Hh - 1));
        float x0f = floorf(px), y0f = floorf(py);
        float wx = px - x0f, wy = py - y0f;
        int x0 = (int)x0f, y0 = (int)y0f;
        int y1 = min(y0 + 1, Hh - 1);
        const bool hi = (x0 == Ww - 1);
        const int xb = hi ? (Ww - 2) : x0;
        const int r0 = y0 * Ww + xb, r1 = y1 * Ww + xb;
        float rb;
        {
            f2 t0 = *(const f2*)(R + r0);
            f2 t1 = *(const f2*)(R + r1);
            float v00 = hi ? t0.y : t0.x, v01 = t0.y;
            float v10 = hi ? t1.y : t1.x, v11 = t1.y;
            float top = v00 * (1.0f - wx) + v01 * wx;
            float bot = v10 * (1.0f - wx) + v11 * wx;
            rb = top * (1.0f - wy) + bot * wy;
        }
        swx[t] = wx; swy[t] = wy; srb[t] = rb;
        sr0[t] = r0 * Cc; sr1[t] = r1 * Cc;
        shi[t] = hi ? 1 : 0;
    }
    __syncthreads();
    {
        const int px = t >> 2, part = t & 3;
        const float wx = swx[px], wy = swy[px], rb = srb[px];
        const bool hi = shi[px] != 0;
        const float* base0 = xnh + (size_t)b * NPIX * Cc + sr0[px];
        const float* base1 = xnh + (size_t)b * NPIX * Cc + sr1[px];
        float* lp = &lds[px * 97 + part * 24];
        #pragma unroll
        for (int i = 0; i < 6; ++i) {
            const int c = part * 24 + i * 4;
            float4 A = *(const float4*)(base0 + c);
            float4 B = *(const float4*)(base0 + Cc + c);
            float4 C = *(const float4*)(base1 + c);
            float4 D = *(const float4*)(base1 + Cc + c);
            #pragma unroll
            for (int k = 0; k < 4; ++k) {
                float a = ((const float*)&A)[k], bb = ((const float*)&B)[k];
                float cc = ((const float*)&C)[k], dd = ((const float*)&D)[k];
                float v00 = hi ? bb : a,  v01 = bb;
                float v10 = hi ? dd : cc, v11 = dd;
                float top = v00 * (1.0f - wx) + v01 * wx;
                float bot = v10 * (1.0f - wx) + v11 * wx;
                lp[i * 4 + k] = top * (1.0f - wy) + bot * wy + rb;
            }
        }
    }
    __syncthreads();
    {
        const int jo = t & 63, cq = t >> 6;   // wave = one cq, lanes = jj
        float* ob = out + (size_t)b * Cc * NPIX + jbase + jo;
        const float* lp = &lds[jo * 97 + cq * 24];
        #pragma unroll
        for (int i = 0; i < 24; ++i) {
            const int c = cq * 24 + i;
            ob[(size_t)c * NPIX] = lp[i];
        }
    }
}

// -------------------- K6-FALLBACK: round-7 NCHW sampler (142.9us proven)
__global__ __launch_bounds__(256, 4) void k_sample(const float* __restrict__ x,
        const float* __restrict__ R, const float* __restrict__ offs,
        const int* __restrict__ iperm, float* __restrict__ out) {
    const int lin = blockIdx.x;
    const int swz = (lin & 7) * 128 + (lin >> 3);
    const int tid = threadIdx.x;
    const int b = swz >> 6;
    const int pix = ((swz & 63) << 8) + tid;
    const int hh = pix >> 7, wwp = pix & 127;
    float o0 = offs[(size_t)b * 2 * NPIX + pix];
    float o1 = offs[(size_t)b * 2 * NPIX + NPIX + pix];
    float gx = -1.0f + (float)wwp * (2.0f / 127.0f) + o0;
    float gy = -1.0f + (float)hh * (2.0f / 127.0f) + o1;
    float px = fminf(fmaxf((gx + 1.0f) * ((float)Ww * 0.5f) - 0.5f, 0.0f), (float)(Ww - 1));
    float py = fminf(fmaxf((gy + 1.0f) * ((float)Hh * 0.5f) - 0.5f, 0.0f), (float)(Hh - 1));
    float x0f = floorf(px), y0f = floorf(py);
    float wx = px - x0f, wy = py - y0f;
    int x0 = (int)x0f, y0 = (int)y0f;
    int y1 = min(y0 + 1, Hh - 1);
    const bool hi = (x0 == Ww - 1);
    const int xb = hi ? (Ww - 2) : x0;
    const int r0 = y0 * Ww + xb, r1 = y1 * Ww + xb;
    float rb;
    {
        f2 t0 = *(const f2*)(R + r0);
        f2 t1 = *(const f2*)(R + r1);
        float v00 = hi ? t0.y : t0.x, v01 = t0.y;
        float v10 = hi ? t1.y : t1.x, v11 = t1.y;
        float top = v00 * (1.0f - wx) + v01 * wx;
        float bot = v10 * (1.0f - wx) + v11 * wx;
        rb = top * (1.0f - wy) + bot * wy;
    }
    const int c0 = blockIdx.y * CPG;
    const int j = iperm[(size_t)b * NPIX + pix];
    const float* xp = x + (size_t)b * Cc * NPIX + (size_t)c0 * NPIX;
    float* op = out + (size_t)b * Cc * NPIX + (size_t)c0 * NPIX + j;
    f2 t0[CPG], t1[CPG];
    #pragma unroll
    for (int c = 0; c < CPG; ++c) {
        const float* xc = xp + (size_t)c * NPIX;
        t0[c] = *(const f2*)(xc + r0);
        t1[c] = *(const f2*)(xc + r1);
    }
    #pragma unroll
    for (int c = 0; c < CPG; ++c) {
        float v00 = hi ? t0[c].y : t0[c].x, v01 = t0[c].y;
        float v10 = hi ? t1[c].y : t1[c].x, v11 = t1[c].y;
        float top = v00 * (1.0f - wx) + v01 * wx;
        float bot = v10 * (1.0f - wx) + v11 * wx;
        op[(size_t)c * NPIX] = top * (1.0f - wy) + bot * wy + rb;
    }
}

extern "C" void kernel_launch(void* const* d_in, const int* in_sizes, int n_in,
                              void* d_out, int out_size, void* d_ws, size_t ws_size,
                              hipStream_t stream) {
    const float* x       = (const float*)d_in[0];
    const float* dw_w    = (const float*)d_in[1];
    const float* dw_b    = (const float*)d_in[2];
    const float* ca_w1   = (const float*)d_in[3];
    const float* ca_w2   = (const float*)d_in[4];
    const float* ln_g    = (const float*)d_in[5];
    const float* ln_b    = (const float*)d_in[6];
    const float* off_w   = (const float*)d_in[7];
    const float* R       = (const float*)d_in[8];
    const float* centers = (const float*)d_in[9];
    float* out = (float*)d_out;

    // workspace: small region (~5.3MB) + optional x_nhwc (100.7MB)
    float* partial = (float*)d_ws;                 // Bc*Cc*8
    float* attn    = partial + Bc * Cc * 8;        // Bc*Cc
    float* offs    = attn + Bc * Cc;               // Bc*2*NPIX
    int*   gid     = (int*)(offs + Bc * 2 * NPIX); // Bc*NPIX
    int*   iperm   = gid + Bc * NPIX;              // Bc*NPIX
    int*   permi   = iperm + Bc * NPIX;            // Bc*NPIX
    float* xnh     = (float*)(permi + Bc * NPIX);  // Bc*NPIX*Cc (optional)

    const size_t small_elems = (size_t)Bc * Cc * 8 + Bc * Cc +
                               (size_t)Bc * 2 * NPIX + 3 * (size_t)Bc * NPIX;
    const size_t need = (small_elems + (size_t)Bc * NPIX * Cc) * 4;
    const int do_nhwc = (ws_size >= need) ? 1 : 0;

    float* f = out;  // conv output lives in out's map region (dead after ln_off)

    hipLaunchKernelGGL(k_conv, dim3(Ww / CTW, Hh / CTH, Bc * Cc), dim3(256), 0,
                       stream, x, dw_w, dw_b, f, partial);
    hipLaunchKernelGGL(k_attn, dim3(Bc), dim3(128), 0, stream,
                       partial, ca_w1, ca_w2, centers, attn, out);
    hipLaunchKernelGGL(k_ln_off, dim3(1024), dim3(256), 0, stream,
                       f, attn, ln_g, ln_b, off_w, offs);
    hipLaunchKernelGGL(k_group, dim3(1024), dim3(256), 0, stream, x, centers, gid);
    hipLaunchKernelGGL(k_sort, dim3(Bc), dim3(256), 0, stream,
                       gid, iperm, permi, out);
    if (do_nhwc) {
        hipLaunchKernelGGL(k_tr, dim3(2048), dim3(256), 0, stream, x, xnh);
        hipLaunchKernelGGL(k_sample_nhwc, dim3(4096), dim3(256), 0, stream,
                           xnh, R, offs, permi, out);
    } else {
        hipLaunchKernelGGL(k_sample, dim3(1024, CGROUPS), dim3(256), 0, stream,
                           x, R, offs, iperm, out);
    }
}